// Round 1
// baseline (235.556 us; speedup 1.0000x reference)
//
#include <hip/hip_runtime.h>
#include <math.h>

// Problem constants
#define BATCH 8
#define NN 64
#define DD 65536            // 64*32*32 feature length (contiguous per [b,n])
#define BPB 64              // blocks per batch -> grid = 512
#define NBLK (BATCH * BPB)
#define KC (DD / BPB)       // 1024 K per block
#define KW (KC / 4)         // 256 K per wave (waves split K)
#define KSTEPS (KW / 32)    // 8 MFMA K-steps per wave
#define NTRI 10             // upper-triangle 16x16 tiles of the 64x64 Gram
#define PSZ (NTRI * 256)    // floats per tri Gram (2560)
#define GRAM_FLOATS (BATCH * PSZ)          // 20480 floats
#define INIT_N (GRAM_FLOATS + BATCH)       // + 8 arrival counters

typedef float  floatx4 __attribute__((ext_vector_type(4)));
typedef __bf16 bf16x8  __attribute__((ext_vector_type(8)));

// Pack 8 fp32 -> 8 bf16 via v_perm_b32 (truncation; bias cancels in the
// scale-invariant cosine ratio — validated R3-R5: absmax 1.5e-5).
static __device__ __forceinline__ bf16x8 cvt8(float4 lo, float4 hi) {
    const unsigned sel = 0x07060302u;
    union { unsigned u[4]; bf16x8 v; } r;
    r.u[0] = __builtin_amdgcn_perm(__float_as_uint(lo.y), __float_as_uint(lo.x), sel);
    r.u[1] = __builtin_amdgcn_perm(__float_as_uint(lo.w), __float_as_uint(lo.z), sel);
    r.u[2] = __builtin_amdgcn_perm(__float_as_uint(hi.y), __float_as_uint(hi.x), sel);
    r.u[3] = __builtin_amdgcn_perm(__float_as_uint(hi.w), __float_as_uint(hi.z), sel);
    return r.v;
}

// ---------------------------------------------------------------------------
// Init: zero tri-gram + arrival counters (workspace is poisoned each iter).
// End-of-dispatch release writes the zeros back past the XCD L2s, so the
// fused kernel's memory-side atomics see a clean base.
// ---------------------------------------------------------------------------
__global__ __launch_bounds__(256) void init_kernel(float* __restrict__ g) {
    int i = blockIdx.x * 256 + threadIdx.x;
    if (i < INIT_N) g[i] = 0.0f;
}

// ---------------------------------------------------------------------------
// Fused kernel.
// Phase 1 (unchanged from the 217.8 µs version — it is HBM-BW-bound):
//   per-chunk partial Gram, upper-triangle tiles only, waves split K,
//   register-double-buffered float4 loads, 10 MFMA accumulators.
// Phase 2: wave 0 atomicAdds the block's 2560-float tri-partial into the
//   global tri-gram (device-scope f32 atomics; order jitter ~1e-9 on sim).
// Phase 3: per-batch arrival counter; the LAST block of each batch runs the
//   CRF iterations in-kernel (agent-scope acquire loads -> LDS), writing out.
// This removes gram_reduce + crf launches and the 5.2 MB part round-trip.
// ---------------------------------------------------------------------------
__global__ __launch_bounds__(256, 3) void fused_kernel(const float* __restrict__ a,
                                                       const float* __restrict__ logits,
                                                       const float* __restrict__ Wm,
                                                       float* __restrict__ gram,
                                                       float* __restrict__ out) {
    __shared__ __align__(16) union {
        float red[3][NTRI][64][4];            // 30 KB — phase-1 cross-wave reduce
        struct {                              // 18.2 KB — phase-3 CRF state
            float G[NN][NN + 1];
            float E[NN];
            float nrm[NN];
            float part[4 * NN];
        } crf;
    } sh;
    __shared__ int lastFlag;

    const int bid = blockIdx.x;
    const int b = bid >> 6;           // / BPB
    const int c = bid & (BPB - 1);

    const int tid  = threadIdx.x;
    const int w    = tid >> 6;        // wave id 0..3 -> K-subchunk
    const int lane = tid & 63;
    const int m    = lane & 15;
    const int q    = lane >> 4;

    const float* base = a + (size_t)b * NN * DD + (size_t)c * KC + (size_t)w * KW
                          + (size_t)m * DD + q * 8;
    const float* p0 = base;                       // rows  0..15
    const float* p1 = base + (size_t)16 * DD;     // rows 16..31
    const float* p2 = base + (size_t)32 * DD;     // rows 32..47
    const float* p3 = base + (size_t)48 * DD;     // rows 48..63

    floatx4 acc[NTRI];
    #pragma unroll
    for (int i = 0; i < NTRI; ++i) acc[i] = (floatx4)0.0f;

    float4 A0, A1, A2, A3, A4, A5, A6, A7;   // buffer A
    float4 B0, B1, B2, B3, B4, B5, B6, B7;   // buffer B

#define LOADSET(R0,R1,R2,R3,R4,R5,R6,R7, o)                                \
    R0 = *(const float4*)(p0 + (o));  R1 = *(const float4*)(p0 + (o) + 4); \
    R2 = *(const float4*)(p1 + (o));  R3 = *(const float4*)(p1 + (o) + 4); \
    R4 = *(const float4*)(p2 + (o));  R5 = *(const float4*)(p2 + (o) + 4); \
    R6 = *(const float4*)(p3 + (o));  R7 = *(const float4*)(p3 + (o) + 4);

    // acc slots: 0:(0,0) 1:(0,1) 2:(0,2) 3:(0,3) 4:(1,1) 5:(1,2) 6:(1,3)
    //            7:(2,2) 8:(2,3) 9:(3,3)
#define MFMASET(R0,R1,R2,R3,R4,R5,R6,R7)                                   \
    {                                                                      \
        bf16x8 f0 = cvt8(R0, R1);                                          \
        bf16x8 f1 = cvt8(R2, R3);                                          \
        bf16x8 f2 = cvt8(R4, R5);                                          \
        bf16x8 f3 = cvt8(R6, R7);                                          \
        acc[0] = __builtin_amdgcn_mfma_f32_16x16x32_bf16(f0, f0, acc[0], 0, 0, 0); \
        acc[1] = __builtin_amdgcn_mfma_f32_16x16x32_bf16(f0, f1, acc[1], 0, 0, 0); \
        acc[2] = __builtin_amdgcn_mfma_f32_16x16x32_bf16(f0, f2, acc[2], 0, 0, 0); \
        acc[3] = __builtin_amdgcn_mfma_f32_16x16x32_bf16(f0, f3, acc[3], 0, 0, 0); \
        acc[4] = __builtin_amdgcn_mfma_f32_16x16x32_bf16(f1, f1, acc[4], 0, 0, 0); \
        acc[5] = __builtin_amdgcn_mfma_f32_16x16x32_bf16(f1, f2, acc[5], 0, 0, 0); \
        acc[6] = __builtin_amdgcn_mfma_f32_16x16x32_bf16(f1, f3, acc[6], 0, 0, 0); \
        acc[7] = __builtin_amdgcn_mfma_f32_16x16x32_bf16(f2, f2, acc[7], 0, 0, 0); \
        acc[8] = __builtin_amdgcn_mfma_f32_16x16x32_bf16(f2, f3, acc[8], 0, 0, 0); \
        acc[9] = __builtin_amdgcn_mfma_f32_16x16x32_bf16(f3, f3, acc[9], 0, 0, 0); \
    }

    LOADSET(A0,A1,A2,A3,A4,A5,A6,A7, 0)
    #pragma unroll
    for (int s = 0; s < KSTEPS; s += 2) {
        LOADSET(B0,B1,B2,B3,B4,B5,B6,B7, (s + 1) * 32)
        MFMASET(A0,A1,A2,A3,A4,A5,A6,A7)
        if (s + 2 < KSTEPS) { LOADSET(A0,A1,A2,A3,A4,A5,A6,A7, (s + 2) * 32) }
        MFMASET(B0,B1,B2,B3,B4,B5,B6,B7)
    }
#undef LOADSET
#undef MFMASET

    // Cross-wave reduce: waves 1..3 dump accs to LDS; wave 0 sums.
    if (w > 0) {
        #pragma unroll
        for (int t = 0; t < NTRI; ++t)
            *(floatx4*)&sh.red[w - 1][t][lane][0] = acc[t];
    }
    __syncthreads();
    if (w == 0) {
        #pragma unroll
        for (int t = 0; t < NTRI; ++t) {
            floatx4 r0 = *(const floatx4*)&sh.red[0][t][lane][0];
            floatx4 r1 = *(const floatx4*)&sh.red[1][t][lane][0];
            floatx4 r2 = *(const floatx4*)&sh.red[2][t][lane][0];
            acc[t] += (r0 + r1) + r2;
        }
        // Phase 2: accumulate into global tri-gram. Slot t holds
        // G[16*ib + 4q + r][16*jb + m] (m89 layout, validated R1-R5).
        float* pg = gram + (size_t)b * PSZ;
        #pragma unroll
        for (int t = 0; t < NTRI; ++t) {
            float* tp = pg + t * 256 + m;
            #pragma unroll
            for (int r = 0; r < 4; ++r)
                atomicAdd(&tp[(q * 4 + r) * 16], acc[t][r]);
        }
        __threadfence();   // gram atomics globally visible before counter bump
    }
    if (tid == 0) {
        unsigned* cnt = (unsigned*)(gram + GRAM_FLOATS);
        unsigned old = atomicAdd(cnt + b, 1u);
        lastFlag = (old == BPB - 1) ? 1 : 0;
    }
    __syncthreads();
    if (!lastFlag) return;

    // -----------------------------------------------------------------------
    // Phase 3: this is the last block of batch b — all 64 partials are in.
    // Load full 64x64 Gram into LDS from the tri layout (K-partial Grams are
    // symmetric, so the transposed slot reconstructs the lower triangle).
    // Agent-scope loads read the coherent point the atomics updated.
    // -----------------------------------------------------------------------
    const float* gb = gram + (size_t)b * PSZ;
    for (int idx = tid; idx < NN * NN; idx += 256) {
        int i  = idx >> 6, j = idx & 63;
        int ti = i >> 4, tj = j >> 4;
        int ib = ti <= tj ? ti : tj;
        int jb = ti <= tj ? tj : ti;
        int slot = ib * 4 - (ib * (ib - 1)) / 2 + (jb - ib);
        int rr = (ti <= tj) ? (i & 15) : (j & 15);
        int cc = (ti <= tj) ? (j & 15) : (i & 15);
        float v = __hip_atomic_load(gb + slot * 256 + rr * 16 + cc,
                                    __ATOMIC_RELAXED, __HIP_MEMORY_SCOPE_AGENT);
        sh.crf.G[i][j] = v;
    }
    __syncthreads();

    const int ci = tid & 63;
    const int jq = tid >> 6;

    if (jq == 0) sh.crf.nrm[ci] = sqrtf(sh.crf.G[ci][ci]);
    sh.crf.E[ci] = 0.0f;
    __syncthreads();

    // pp in place: each (i,j) element owned by exactly one thread.
    const float ni = sh.crf.nrm[ci];
    #pragma unroll
    for (int jj = 0; jj < 16; ++jj) {
        int j = jq * 16 + jj;
        float wsym = 0.5f * (Wm[ci * NN + j] + Wm[j * NN + ci]);
        sh.crf.G[ci][j] = sh.crf.G[ci][j] / (ni * sh.crf.nrm[j] + 1e-6f) * wsym;
    }
    const float li = logits[b * NN + ci];
    __syncthreads();

    for (int it = 0; it < 10; ++it) {
        float acc2 = 0.0f;
        #pragma unroll
        for (int jj = 0; jj < 16; ++jj) {
            int j = jq * 16 + jj;
            float t = li + sh.crf.E[j];
            float s = 1.0f / (1.0f + expf(-t));
            acc2 = fmaf(2.0f * s - 1.0f, sh.crf.G[ci][j], acc2);
        }
        sh.crf.part[jq * NN + ci] = acc2;
        __syncthreads();
        if (jq == 0)
            sh.crf.E[ci] = sh.crf.part[ci] + sh.crf.part[NN + ci]
                         + sh.crf.part[2 * NN + ci] + sh.crf.part[3 * NN + ci];
        __syncthreads();
    }

    if (tid < 64) {
        float s = sh.crf.E[tid];
        for (int off = 32; off > 0; off >>= 1) s += __shfl_down(s, off);
        float meanE = __shfl(s, 0) * (1.0f / 64.0f);
        out[b * NN + tid] = logits[b * NN + tid] + meanE;
    }
}

extern "C" void kernel_launch(void* const* d_in, const int* in_sizes, int n_in,
                              void* d_out, int out_size, void* d_ws, size_t ws_size,
                              hipStream_t stream) {
    const float* a      = (const float*)d_in[0];  // [8,64,64,32,32]
    const float* logits = (const float*)d_in[1];  // [8,64]
    const float* Wm     = (const float*)d_in[2];  // [1,64,64]
    float* out  = (float*)d_out;                  // [8,64]

    float* gram = (float*)d_ws;                   // [8][2560] tri + 8 counters

    init_kernel<<<(INIT_N + 255) / 256, 256, 0, stream>>>(gram);
    fused_kernel<<<NBLK, 256, 0, stream>>>(a, logits, Wm, gram, out);
}